// Round 2
// baseline (207.073 us; speedup 1.0000x reference)
//
#include <hip/hip_runtime.h>
#include <cstddef>

typedef _Float16 f16;
typedef _Float16 f16x8 __attribute__((ext_vector_type(8)));
typedef _Float16 f16x4 __attribute__((ext_vector_type(4)));
typedef _Float16 f16x2 __attribute__((ext_vector_type(2)));
typedef float f32x4 __attribute__((ext_vector_type(4)));
typedef float f32x16 __attribute__((ext_vector_type(16)));
typedef unsigned int u32;

__device__ inline float exp2_fast(float x) {
  float r;
  asm("v_exp_f32 %0, %1" : "=v"(r) : "v"(x));
  return r;
}

// pack two f32 -> f16x2 word (RTZ), as int for cross-lane ops
__device__ inline int pk2(float x, float y) {
  return __builtin_bit_cast(int, __builtin_amdgcn_cvt_pkrtz(x, y));
}

__device__ inline f16x2 pk2h(float x, float y) {
  return __builtin_bit_cast(f16x2, __builtin_amdgcn_cvt_pkrtz(x, y));
}

// v_permlane32_swap_b32: new_a[32:63] = old_b[0:31], new_b[0:31] = old_a[32:63]
__device__ inline void permlane32_swap(int& a, int& b) {
  asm volatile("v_permlane32_swap_b32 %0, %1" : "+v"(a), "+v"(b));
}

// ---------------------------------------------------------------------------
// Fused prep: blocks [0,8192) stream-convert x_q/x_kv f32->f16;
// blocks [8192,12288) transpose+convert the three weight matrices.
// ---------------------------------------------------------------------------
__global__ __launch_bounds__(256) void prep(
    const float* __restrict__ xq, const float* __restrict__ xkv,
    f16* __restrict__ oq, f16* __restrict__ okv,
    const float* __restrict__ Wq, const float* __restrict__ Wkv,
    const float* __restrict__ Wp, f16* __restrict__ Wqt,
    f16* __restrict__ Wkvt, f16* __restrict__ Wpt) {
  __shared__ float t[32][33];
  int bid = blockIdx.x;
  if (bid < 8192) {
    const float* in = (bid < 4096) ? xq : xkv;
    f16* out = (bid < 4096) ? oq : okv;
    int i = ((bid & 4095) * 256 + threadIdx.x) * 4;
    float4 v = *(const float4*)&in[i];
    f16x4 h;
    h[0] = (f16)v.x; h[1] = (f16)v.y; h[2] = (f16)v.z; h[3] = (f16)v.w;
    *(f16x4*)&out[i] = h;
  } else {
    int zz = bid - 8192;
    int bx = zz & 31, by = (zz >> 5) & 31, z = zz >> 10;
    const float* in;
    f16* out;
    int N = 1024, extra = 0;
    if (z == 0) { in = Wq; out = Wqt; }
    else if (z == 3) { in = Wp; out = Wpt; }
    else { in = Wkv; out = Wkvt; N = 2048; extra = (z - 1) * 1024; }
    int tx = threadIdx.x % 32, ty = threadIdx.x / 32;
    int n0 = bx * 32 + extra, k0 = by * 32;
#pragma unroll
    for (int i = 0; i < 32; i += 8)
      t[ty + i][tx] = in[(size_t)(k0 + ty + i) * N + n0 + tx];
    __syncthreads();
#pragma unroll
    for (int i = 0; i < 32; i += 8)
      out[(size_t)(n0 + ty + i) * 1024 + k0 + tx] = (f16)t[tx][ty + i];
  }
}

// ---------------------------------------------------------------------------
// GEMM body (unchanged, control): register-prefetch pipeline + XOR-swizzled
// LDS. BM=128, BN templated, BK=64, 256 thr = 4 waves (2x2), 16x16x32 MFMA.
// ---------------------------------------------------------------------------
template <int BN, typename CT>
__device__ __forceinline__ void gemm_body(
    const f16* __restrict__ A, const f16* __restrict__ Bt, CT* __restrict__ C,
    int bid, int M, int N, int K, float scale, f16* As, f16* Bs) {
  constexpr int NT = BN / 32;
  constexpr int BI = BN / 32;
  const int nb = N / BN;
  const int m0 = (bid / nb) * 128;
  const int n0 = (bid % nb) * BN;
  const int tid = threadIdx.x;
  const int w = tid >> 6, lane = tid & 63;
  const int l16 = lane & 15, quad = lane >> 4;
  const int wrow = (w >> 1) * 64, wcol = (w & 1) * (BN / 2);
  const int sr = tid >> 3, sc8 = tid & 7;
  const int wc8 = sc8 ^ (sr & 7);  // swizzled write col-group

  f32x4 acc[4][NT] = {};
  f16x8 ar[4], br[BI];

#pragma unroll
  for (int i = 0; i < 4; i++)
    ar[i] = *(const f16x8*)&A[(size_t)(m0 + sr + i * 32) * K + sc8 * 8];
#pragma unroll
  for (int i = 0; i < BI; i++)
    br[i] = *(const f16x8*)&Bt[(size_t)(n0 + sr + i * 32) * K + sc8 * 8];

  for (int k0 = 0; k0 < K; k0 += 64) {
    // ---- commit prefetched tile (swizzled, bank-floor b128 writes) ----
#pragma unroll
    for (int i = 0; i < 4; i++)
      *(f16x8*)&As[(sr + i * 32) * 64 + wc8 * 8] = ar[i];
#pragma unroll
    for (int i = 0; i < BI; i++)
      *(f16x8*)&Bs[(sr + i * 32) * 64 + wc8 * 8] = br[i];
    __syncthreads();

    // ---- issue next tile's loads (hidden under this tile's compute) ----
    if (k0 + 64 < K) {
#pragma unroll
      for (int i = 0; i < 4; i++)
        ar[i] = *(const f16x8*)&A[(size_t)(m0 + sr + i * 32) * K + k0 + 64 + sc8 * 8];
#pragma unroll
      for (int i = 0; i < BI; i++)
        br[i] = *(const f16x8*)&Bt[(size_t)(n0 + sr + i * 32) * K + k0 + 64 + sc8 * 8];
    }

    // ---- fragments (swizzled reads, bank floor) + MFMA ----
    f16x8 bf[NT][2];
#pragma unroll
    for (int nt = 0; nt < NT; nt++) {
      const int row = wcol + nt * 16 + l16;
#pragma unroll
      for (int s = 0; s < 2; s++)
        bf[nt][s] = *(const f16x8*)&Bs[row * 64 + (((s * 4 + quad) ^ (row & 7)) << 3)];
    }
#pragma unroll
    for (int mt = 0; mt < 4; mt++) {
      const int row = wrow + mt * 16 + l16;
      f16x8 af0 = *(const f16x8*)&As[row * 64 + ((quad ^ (row & 7)) << 3)];
      f16x8 af1 = *(const f16x8*)&As[row * 64 + (((4 + quad) ^ (row & 7)) << 3)];
#pragma unroll
      for (int nt = 0; nt < NT; nt++) {
        acc[mt][nt] = __builtin_amdgcn_mfma_f32_16x16x32_f16(af0, bf[nt][0], acc[mt][nt], 0, 0, 0);
        acc[mt][nt] = __builtin_amdgcn_mfma_f32_16x16x32_f16(af1, bf[nt][1], acc[mt][nt], 0, 0, 0);
      }
    }
    __syncthreads();
  }

#pragma unroll
  for (int mt = 0; mt < 4; mt++)
#pragma unroll
    for (int nt = 0; nt < NT; nt++)
#pragma unroll
      for (int r = 0; r < 4; r++) {
        int row = m0 + wrow + mt * 16 + quad * 4 + r;
        int col = n0 + wcol + nt * 16 + l16;
        C[(size_t)row * N + col] = (CT)(acc[mt][nt][r] * scale);
      }
}

// Fused Q + KV projection GEMMs (unchanged, control).
__global__ __launch_bounds__(256, 3) void qkv_gemm(
    const f16* __restrict__ Xq, const f16* __restrict__ Wqt, f16* __restrict__ Qh,
    const f16* __restrict__ Xkv, const f16* __restrict__ Wkvt, f16* __restrict__ KVh,
    float sc_q) {
  __shared__ f16 As[128 * 64];
  __shared__ f16 Bs[128 * 64];
  if (blockIdx.x < 256)
    gemm_body<128, f16>(Xq, Wqt, Qh, blockIdx.x, 4096, 1024, 1024, sc_q, As, Bs);
  else
    gemm_body<128, f16>(Xkv, Wkvt, KVh, blockIdx.x - 256, 4096, 2048, 1024, 1.0f, As, Bs);
}

template <int BN, typename CT>
__global__ __launch_bounds__(256, 2) void gemm_lds(
    const f16* __restrict__ A, const f16* __restrict__ Bt, CT* __restrict__ C,
    int M, int N, int K, float scale) {
  __shared__ f16 As[128 * 64];
  __shared__ f16 Bs[BN * 64];
  gemm_body<BN, CT>(A, Bt, C, blockIdx.x, M, N, K, scale, As, Bs);
}

// ---------------------------------------------------------------------------
// Flash attention, round 8: softmax VALU-path reduction.
//  - P never touches LDS: C-layout regs are packed with v_cvt_pkrtz_f16_f32
//    and redistributed across the lane/lane^32 pair with
//    v_permlane32_swap_b32 to form the PV B-fragments directly.
//    (C reg r holds kv=(r&3)+8*(r>>2)+4e; B-frag wants k=e*8+j per 16-slice;
//    swap of pk(p0,p1)<->pk(p4,p5) yields words w0/w2 for both halves.)
//    Kills the 8-way-conflicted Psw stores/reads (was ~all of the 6.3M
//    SQ_LDS_BANK_CONFLICT) and 32 scalar cvts per iter.
//  - defer-max (THR=8 log2-domain): skip O-rescale when tile max hasn't
//    grown; P bounded by 2^8, safe in f16.
//  - max3-fusable tree max + 4-way ssum accumulators (dep depth 31 -> ~5;
//    matters at 2 waves/SIMD).
//  LDS: 18432 B (Ks+Vt only); epilogue reuses it as f16 [32q][72] per wave.
// ---------------------------------------------------------------------------
__global__ __launch_bounds__(256) void attn_kernel(
    const f16* __restrict__ Qh, const f16* __restrict__ KVh, f16* __restrict__ Yh) {
  __shared__ f16 smem[9216];
  f16* Ks = smem;                      // [64 kv][72]
  f16* Vt = smem + 64 * 72;            // [64 d][72] swizzled

  const int bid = blockIdx.x;
  const int hb = bid & 31;
  const int qt = bid >> 5;
  const int h = hb >> 1, b = hb & 1;
  const int tid = threadIdx.x;
  const int w = tid >> 6, lane = tid & 63;
  const int l31 = lane & 31, e = lane >> 5;

  const size_t qrow0 = (size_t)b * 2048 + (size_t)qt * 128;
  const size_t kvrow0 = (size_t)b * 2048;

  f16x8 qf[4];
#pragma unroll
  for (int ks = 0; ks < 4; ks++)
    qf[ks] = *(const f16x8*)&Qh[(qrow0 + w * 32 + l31) * 1024 + h * 64 + ks * 16 + e * 8];

  float m_run = -1e30f, l_run = 0.0f;
  f32x16 o_acc[2] = {};

  const int ksr = tid >> 2, ksc = (tid & 3) << 4;
  const int vkv0 = (tid >> 3) * 2;
  const int vd0 = (tid & 7) * 8;
  const int vcol = ((((vkv0 >> 3) ^ (tid & 7)) << 3) | (vkv0 & 7));

  f16x8 kr0, kr1, vr0, vr1;
  {
    const f16* kb = &KVh[(kvrow0 + ksr) * 2048 + h * 64 + ksc];
    kr0 = *(const f16x8*)kb;
    kr1 = *(const f16x8*)(kb + 8);
    const f16* vb = &KVh[(kvrow0 + vkv0) * 2048 + 1024 + h * 64 + vd0];
    vr0 = *(const f16x8*)vb;
    vr1 = *(const f16x8*)(vb + 2048);
  }

  for (int t = 0; t < 32; t++) {
    *(f16x8*)&Ks[ksr * 72 + ksc] = kr0;
    *(f16x8*)&Ks[ksr * 72 + ksc + 8] = kr1;
#pragma unroll
    for (int j = 0; j < 8; j++) {
      f16x2 p; p[0] = vr0[j]; p[1] = vr1[j];
      *(f16x2*)&Vt[(vd0 + j) * 72 + vcol] = p;
    }
    __syncthreads();

    if (t + 1 < 32) {
      const f16* kb = &KVh[(kvrow0 + (t + 1) * 64 + ksr) * 2048 + h * 64 + ksc];
      kr0 = *(const f16x8*)kb;
      kr1 = *(const f16x8*)(kb + 8);
      const f16* vb = &KVh[(kvrow0 + (t + 1) * 64 + vkv0) * 2048 + 1024 + h * 64 + vd0];
      vr0 = *(const f16x8*)vb;
      vr1 = *(const f16x8*)(vb + 2048);
    }

    // ---- S = K @ Q^T : lane(q=l31,e) reg r holds kv=(r&3)+8*(r>>2)+4e ----
    f32x16 sacc[2] = {};
#pragma unroll
    for (int kvt = 0; kvt < 2; kvt++)
#pragma unroll
      for (int ks = 0; ks < 4; ks++) {
        f16x8 a = *(const f16x8*)&Ks[(kvt * 32 + l31) * 72 + ks * 16 + e * 8];
        sacc[kvt] = __builtin_amdgcn_mfma_f32_32x32x16_f16(a, qf[ks], sacc[kvt], 0, 0, 0);
      }

    // ---- tree max (max3-fusable, depth ~5) ----
    float mxa[4];
#pragma unroll
    for (int j = 0; j < 4; j++) {
      float a = fmaxf(fmaxf(sacc[0][j], sacc[0][j + 4]),
                      fmaxf(sacc[0][j + 8], sacc[0][j + 12]));
      float bb = fmaxf(fmaxf(sacc[1][j], sacc[1][j + 4]),
                       fmaxf(sacc[1][j + 8], sacc[1][j + 12]));
      mxa[j] = fmaxf(a, bb);
    }
    float mx = fmaxf(fmaxf(mxa[0], mxa[1]), fmaxf(mxa[2], mxa[3]));
    mx = fmaxf(mx, __shfl_xor(mx, 32, 64));

    // ---- defer-max: only rescale when the running max grew by > 8 ----
    if (!__all(mx <= m_run + 8.0f)) {
      float mnew = fmaxf(m_run, mx);
      float alpha = exp2_fast(m_run - mnew);
      m_run = mnew;
      l_run *= alpha;
#pragma unroll
      for (int r = 0; r < 16; r++) { o_acc[0][r] *= alpha; o_acc[1][r] *= alpha; }
    }

    // ---- P = exp2(S - m), 4-way split sum ----
    float ss0 = 0.0f, ss1 = 0.0f, ss2 = 0.0f, ss3 = 0.0f;
#pragma unroll
    for (int kvt = 0; kvt < 2; kvt++)
#pragma unroll
      for (int r = 0; r < 16; r += 4) {
        float p0 = exp2_fast(sacc[kvt][r + 0] - m_run);
        float p1 = exp2_fast(sacc[kvt][r + 1] - m_run);
        float p2 = exp2_fast(sacc[kvt][r + 2] - m_run);
        float p3 = exp2_fast(sacc[kvt][r + 3] - m_run);
        sacc[kvt][r + 0] = p0; sacc[kvt][r + 1] = p1;
        sacc[kvt][r + 2] = p2; sacc[kvt][r + 3] = p3;
        ss0 += p0; ss1 += p1; ss2 += p2; ss3 += p3;
      }
    float ssum = (ss0 + ss1) + (ss2 + ss3);
    ssum += __shfl_xor(ssum, 32, 64);
    l_run += ssum;

    // ---- P -> f16 B-fragments fully in-register (cvt_pkrtz + permlane32) ----
    f16x8 pf[4];
#pragma unroll
    for (int kvt = 0; kvt < 2; kvt++)
#pragma unroll
      for (int half = 0; half < 2; half++) {
        const int h8 = half * 8;
        int a0 = pk2(sacc[kvt][h8 + 0], sacc[kvt][h8 + 1]);
        int b0 = pk2(sacc[kvt][h8 + 4], sacc[kvt][h8 + 5]);
        int a1 = pk2(sacc[kvt][h8 + 2], sacc[kvt][h8 + 3]);
        int b1 = pk2(sacc[kvt][h8 + 6], sacc[kvt][h8 + 7]);
        permlane32_swap(a0, b0);   // a0 -> w0, b0 -> w2
        permlane32_swap(a1, b1);   // a1 -> w1, b1 -> w3
        union { int i[4]; f16x8 v; } u;
        u.i[0] = a0; u.i[1] = a1; u.i[2] = b0; u.i[3] = b1;
        pf[kvt * 2 + half] = u.v;
      }

    // ---- O += V^T @ P ----
#pragma unroll
    for (int dt = 0; dt < 2; dt++) {
      const int d = dt * 32 + l31;
      const int dx = d >> 3;
#pragma unroll
      for (int ks = 0; ks < 4; ks++) {
        f16x8 va = *(const f16x8*)&Vt[d * 72 + (((ks * 2 + e) ^ dx) << 3)];
        o_acc[dt] = __builtin_amdgcn_mfma_f32_32x32x16_f16(va, pf[ks], o_acc[dt], 0, 0, 0);
      }
    }
    __syncthreads();
  }

  // ---- epilogue: normalize, reshuffle via LDS (f16), coalesced Yh write ----
  float linv = 1.0f / l_run;
  f16* Of = smem + w * 32 * 72;  // [32 q][72], per-wave region (Ks/Vt dead)
#pragma unroll
  for (int dt = 0; dt < 2; dt++)
#pragma unroll
    for (int r2 = 0; r2 < 4; r2++) {
      f16x2 h0 = pk2h(o_acc[dt][r2 * 4 + 0] * linv, o_acc[dt][r2 * 4 + 1] * linv);
      f16x2 h1 = pk2h(o_acc[dt][r2 * 4 + 2] * linv, o_acc[dt][r2 * 4 + 3] * linv);
      f16x4 hh; hh[0] = h0[0]; hh[1] = h0[1]; hh[2] = h1[0]; hh[3] = h1[1];
      *(f16x4*)&Of[l31 * 72 + dt * 32 + r2 * 8 + e * 4] = hh;
    }
  const int qq = lane >> 1, dh = (lane & 1) * 32;
#pragma unroll
  for (int j = 0; j < 4; j++) {
    f16x8 v = *(const f16x8*)&Of[qq * 72 + dh + j * 8];
    *(f16x8*)&Yh[(qrow0 + w * 32 + qq) * 1024 + h * 64 + dh + j * 8] = v;
  }
}

// ---------------------------------------------------------------------------
extern "C" void kernel_launch(void* const* d_in, const int* in_sizes, int n_in,
                              void* d_out, int out_size, void* d_ws, size_t ws_size,
                              hipStream_t stream) {
  const float* x_q  = (const float*)d_in[0];
  const float* x_kv = (const float*)d_in[1];
  const float* W_q  = (const float*)d_in[2];
  const float* W_kv = (const float*)d_in[3];
  const float* W_p  = (const float*)d_in[4];
  float* out = (float*)d_out;

  f16* Wq_t  = (f16*)d_ws;                       // [1024][1024]
  f16* Wkv_t = Wq_t  + (size_t)1024 * 1024;      // [2048][1024]
  f16* Wp_t  = Wkv_t + (size_t)2048 * 1024;      // [1024][1024]
  f16* Qh    = Wp_t  + (size_t)1024 * 1024;      // [4096][1024]
  f16* KVh   = Qh    + (size_t)4096 * 1024;      // [4096][2048]
  f16* Yh    = KVh   + (size_t)4096 * 2048;      // [4096][1024]
  f16* Xq_h  = Yh;                               // alias (dead after qkv_gemm)
  f16* Xkv_h = Yh    + (size_t)4096 * 1024;      // [4096][1024]

  prep<<<12288, 256, 0, stream>>>(x_q, x_kv, Xq_h, Xkv_h,
                                  W_q, W_kv, W_p, Wq_t, Wkv_t, Wp_t);

  const float SC = 11.5415603f;  // 8 * log2(e)
  qkv_gemm<<<768, 256, 0, stream>>>(Xq_h, Wq_t, Qh, Xkv_h, Wkv_t, KVh, SC);

  attn_kernel<<<512, 256, 0, stream>>>(Qh, KVh, Yh);

  gemm_lds<64, float><<<512, 256, 0, stream>>>(Yh, Wp_t, out, 4096, 1024, 1024, 1.0f);
}

// Round 3
// 203.863 us; speedup vs baseline: 1.0157x; 1.0157x over previous
//
#include <hip/hip_runtime.h>
#include <cstddef>

typedef _Float16 f16;
typedef _Float16 f16x8 __attribute__((ext_vector_type(8)));
typedef _Float16 f16x4 __attribute__((ext_vector_type(4)));
typedef _Float16 f16x2 __attribute__((ext_vector_type(2)));
typedef float f32x4 __attribute__((ext_vector_type(4)));
typedef float f32x16 __attribute__((ext_vector_type(16)));
typedef unsigned int u32;

__device__ inline float exp2_fast(float x) {
  float r;
  asm("v_exp_f32 %0, %1" : "=v"(r) : "v"(x));
  return r;
}

// pack two f32 -> f16x2 word (RTZ), as int for cross-lane ops
__device__ inline int pk2(float x, float y) {
  return __builtin_bit_cast(int, __builtin_amdgcn_cvt_pkrtz(x, y));
}

__device__ inline f16x2 pk2h(float x, float y) {
  return __builtin_bit_cast(f16x2, __builtin_amdgcn_cvt_pkrtz(x, y));
}

// v_permlane32_swap_b32: new_a[32:63] = old_b[0:31], new_b[0:31] = old_a[32:63]
__device__ inline void permlane32_swap(int& a, int& b) {
  asm volatile("v_permlane32_swap_b32 %0, %1" : "+v"(a), "+v"(b));
}

// ---------------------------------------------------------------------------
// Fused prep (unchanged): blocks [0,8192) stream-convert x_q/x_kv f32->f16;
// blocks [8192,12288) transpose+convert the three weight matrices.
// ---------------------------------------------------------------------------
__global__ __launch_bounds__(256) void prep(
    const float* __restrict__ xq, const float* __restrict__ xkv,
    f16* __restrict__ oq, f16* __restrict__ okv,
    const float* __restrict__ Wq, const float* __restrict__ Wkv,
    const float* __restrict__ Wp, f16* __restrict__ Wqt,
    f16* __restrict__ Wkvt, f16* __restrict__ Wpt) {
  __shared__ float t[32][33];
  int bid = blockIdx.x;
  if (bid < 8192) {
    const float* in = (bid < 4096) ? xq : xkv;
    f16* out = (bid < 4096) ? oq : okv;
    int i = ((bid & 4095) * 256 + threadIdx.x) * 4;
    float4 v = *(const float4*)&in[i];
    f16x4 h;
    h[0] = (f16)v.x; h[1] = (f16)v.y; h[2] = (f16)v.z; h[3] = (f16)v.w;
    *(f16x4*)&out[i] = h;
  } else {
    int zz = bid - 8192;
    int bx = zz & 31, by = (zz >> 5) & 31, z = zz >> 10;
    const float* in;
    f16* out;
    int N = 1024, extra = 0;
    if (z == 0) { in = Wq; out = Wqt; }
    else if (z == 3) { in = Wp; out = Wpt; }
    else { in = Wkv; out = Wkvt; N = 2048; extra = (z - 1) * 1024; }
    int tx = threadIdx.x % 32, ty = threadIdx.x / 32;
    int n0 = bx * 32 + extra, k0 = by * 32;
#pragma unroll
    for (int i = 0; i < 32; i += 8)
      t[ty + i][tx] = in[(size_t)(k0 + ty + i) * N + n0 + tx];
    __syncthreads();
#pragma unroll
    for (int i = 0; i < 32; i += 8)
      out[(size_t)(n0 + ty + i) * 1024 + k0 + tx] = (f16)t[tx][ty + i];
  }
}

// ---------------------------------------------------------------------------
// GEMM body (unchanged, control): register-prefetch pipeline + XOR-swizzled
// LDS. BM=128, BN templated, BK=64, 256 thr = 4 waves (2x2), 16x16x32 MFMA.
// ---------------------------------------------------------------------------
template <int BN, typename CT>
__device__ __forceinline__ void gemm_body(
    const f16* __restrict__ A, const f16* __restrict__ Bt, CT* __restrict__ C,
    int bid, int M, int N, int K, float scale, f16* As, f16* Bs) {
  constexpr int NT = BN / 32;
  constexpr int BI = BN / 32;
  const int nb = N / BN;
  const int m0 = (bid / nb) * 128;
  const int n0 = (bid % nb) * BN;
  const int tid = threadIdx.x;
  const int w = tid >> 6, lane = tid & 63;
  const int l16 = lane & 15, quad = lane >> 4;
  const int wrow = (w >> 1) * 64, wcol = (w & 1) * (BN / 2);
  const int sr = tid >> 3, sc8 = tid & 7;
  const int wc8 = sc8 ^ (sr & 7);  // swizzled write col-group

  f32x4 acc[4][NT] = {};
  f16x8 ar[4], br[BI];

#pragma unroll
  for (int i = 0; i < 4; i++)
    ar[i] = *(const f16x8*)&A[(size_t)(m0 + sr + i * 32) * K + sc8 * 8];
#pragma unroll
  for (int i = 0; i < BI; i++)
    br[i] = *(const f16x8*)&Bt[(size_t)(n0 + sr + i * 32) * K + sc8 * 8];

  for (int k0 = 0; k0 < K; k0 += 64) {
    // ---- commit prefetched tile (swizzled, bank-floor b128 writes) ----
#pragma unroll
    for (int i = 0; i < 4; i++)
      *(f16x8*)&As[(sr + i * 32) * 64 + wc8 * 8] = ar[i];
#pragma unroll
    for (int i = 0; i < BI; i++)
      *(f16x8*)&Bs[(sr + i * 32) * 64 + wc8 * 8] = br[i];
    __syncthreads();

    // ---- issue next tile's loads (hidden under this tile's compute) ----
    if (k0 + 64 < K) {
#pragma unroll
      for (int i = 0; i < 4; i++)
        ar[i] = *(const f16x8*)&A[(size_t)(m0 + sr + i * 32) * K + k0 + 64 + sc8 * 8];
#pragma unroll
      for (int i = 0; i < BI; i++)
        br[i] = *(const f16x8*)&Bt[(size_t)(n0 + sr + i * 32) * K + k0 + 64 + sc8 * 8];
    }

    // ---- fragments (swizzled reads, bank floor) + MFMA ----
    f16x8 bf[NT][2];
#pragma unroll
    for (int nt = 0; nt < NT; nt++) {
      const int row = wcol + nt * 16 + l16;
#pragma unroll
      for (int s = 0; s < 2; s++)
        bf[nt][s] = *(const f16x8*)&Bs[row * 64 + (((s * 4 + quad) ^ (row & 7)) << 3)];
    }
#pragma unroll
    for (int mt = 0; mt < 4; mt++) {
      const int row = wrow + mt * 16 + l16;
      f16x8 af0 = *(const f16x8*)&As[row * 64 + ((quad ^ (row & 7)) << 3)];
      f16x8 af1 = *(const f16x8*)&As[row * 64 + (((4 + quad) ^ (row & 7)) << 3)];
#pragma unroll
      for (int nt = 0; nt < NT; nt++) {
        acc[mt][nt] = __builtin_amdgcn_mfma_f32_16x16x32_f16(af0, bf[nt][0], acc[mt][nt], 0, 0, 0);
        acc[mt][nt] = __builtin_amdgcn_mfma_f32_16x16x32_f16(af1, bf[nt][1], acc[mt][nt], 0, 0, 0);
      }
    }
    __syncthreads();
  }

#pragma unroll
  for (int mt = 0; mt < 4; mt++)
#pragma unroll
    for (int nt = 0; nt < NT; nt++)
#pragma unroll
      for (int r = 0; r < 4; r++) {
        int row = m0 + wrow + mt * 16 + quad * 4 + r;
        int col = n0 + wcol + nt * 16 + l16;
        C[(size_t)row * N + col] = (CT)(acc[mt][nt][r] * scale);
      }
}

// Fused Q + KV projection GEMMs (unchanged, control).
__global__ __launch_bounds__(256, 3) void qkv_gemm(
    const f16* __restrict__ Xq, const f16* __restrict__ Wqt, f16* __restrict__ Qh,
    const f16* __restrict__ Xkv, const f16* __restrict__ Wkvt, f16* __restrict__ KVh,
    float sc_q) {
  __shared__ f16 As[128 * 64];
  __shared__ f16 Bs[128 * 64];
  if (blockIdx.x < 256)
    gemm_body<128, f16>(Xq, Wqt, Qh, blockIdx.x, 4096, 1024, 1024, sc_q, As, Bs);
  else
    gemm_body<128, f16>(Xkv, Wkvt, KVh, blockIdx.x - 256, 4096, 2048, 1024, 1.0f, As, Bs);
}

template <int BN, typename CT>
__global__ __launch_bounds__(256, 2) void gemm_lds(
    const f16* __restrict__ A, const f16* __restrict__ Bt, CT* __restrict__ C,
    int M, int N, int K, float scale) {
  __shared__ f16 As[128 * 64];
  __shared__ f16 Bs[BN * 64];
  gemm_body<BN, CT>(A, Bt, C, blockIdx.x, M, N, K, scale, As, Bs);
}

// ---------------------------------------------------------------------------
// Flash attention, round 9: KV-split occupancy fix.
// Round-8 post-mortem: removing VALU work (in-reg P) changed nothing ->
// kernel is dependency-stall-bound at 2 waves/SIMD (512 blk x 4 waves =
// 8 waves/CU; grid is the occupancy limiter, and q is fully parallel
// already). This round: 8 waves/block (512 thr); waves {qw, half}; each
// half streams its own 1024 KV rows through its own LDS double-buffer
// pair (16 iters, barrier count halved), then a one-time in-LDS merge
// combines the two (m,l,O) partials. 2 blocks/CU x 8 waves = 4 waves/SIMD.
// LDS: 36864 B = 2 halves x (Ks[64][72] + Vt[64][72]).
// ---------------------------------------------------------------------------
__global__ __launch_bounds__(512, 4) void attn_kernel(
    const f16* __restrict__ Qh, const f16* __restrict__ KVh, f16* __restrict__ Yh) {
  __shared__ f16 smem[18432];  // 36864 B

  const int bid = blockIdx.x;
  const int hb = bid & 31;
  const int qt = bid >> 5;
  const int h = hb >> 1, b = hb & 1;
  const int tid = threadIdx.x;
  const int w = tid >> 6, lane = tid & 63;
  const int l31 = lane & 31, e = lane >> 5;
  const int qw = w & 3, half = w >> 2;
  const int tl = tid & 255;  // staging index within the half

  f16* Ks = smem + half * (2 * 64 * 72);  // this half's K tile [64 kv][72]
  f16* Vt = Ks + 64 * 72;                 // this half's V^T tile [64 d][72]

  const size_t qrow0 = (size_t)b * 2048 + (size_t)qt * 128;
  const size_t kvrow0 = (size_t)b * 2048 + (size_t)half * 1024;

  f16x8 qf[4];
#pragma unroll
  for (int ks = 0; ks < 4; ks++)
    qf[ks] = *(const f16x8*)&Qh[(qrow0 + qw * 32 + l31) * 1024 + h * 64 + ks * 16 + e * 8];

  float m_run = -1e30f, l_run = 0.0f;
  f32x16 o_acc[2] = {};

  const int ksr = tl >> 2, ksc = (tl & 3) << 4;
  const int vkv0 = (tl >> 3) * 2;
  const int vd0 = (tl & 7) * 8;
  const int vcol = ((((vkv0 >> 3) ^ (tl & 7)) << 3) | (vkv0 & 7));

  f16x8 kr0, kr1, vr0, vr1;
  {
    const f16* kb = &KVh[(kvrow0 + ksr) * 2048 + h * 64 + ksc];
    kr0 = *(const f16x8*)kb;
    kr1 = *(const f16x8*)(kb + 8);
    const f16* vb = &KVh[(kvrow0 + vkv0) * 2048 + 1024 + h * 64 + vd0];
    vr0 = *(const f16x8*)vb;
    vr1 = *(const f16x8*)(vb + 2048);
  }

  for (int t = 0; t < 16; t++) {
    *(f16x8*)&Ks[ksr * 72 + ksc] = kr0;
    *(f16x8*)&Ks[ksr * 72 + ksc + 8] = kr1;
#pragma unroll
    for (int j = 0; j < 8; j++) {
      f16x2 p; p[0] = vr0[j]; p[1] = vr1[j];
      *(f16x2*)&Vt[(vd0 + j) * 72 + vcol] = p;
    }
    __syncthreads();

    if (t + 1 < 16) {
      const f16* kb = &KVh[(kvrow0 + (t + 1) * 64 + ksr) * 2048 + h * 64 + ksc];
      kr0 = *(const f16x8*)kb;
      kr1 = *(const f16x8*)(kb + 8);
      const f16* vb = &KVh[(kvrow0 + (t + 1) * 64 + vkv0) * 2048 + 1024 + h * 64 + vd0];
      vr0 = *(const f16x8*)vb;
      vr1 = *(const f16x8*)(vb + 2048);
    }

    // ---- S = K @ Q^T : lane(q=l31,e) reg r holds kv=(r&3)+8*(r>>2)+4e ----
    f32x16 sacc[2] = {};
#pragma unroll
    for (int kvt = 0; kvt < 2; kvt++)
#pragma unroll
      for (int ks = 0; ks < 4; ks++) {
        f16x8 a = *(const f16x8*)&Ks[(kvt * 32 + l31) * 72 + ks * 16 + e * 8];
        sacc[kvt] = __builtin_amdgcn_mfma_f32_32x32x16_f16(a, qf[ks], sacc[kvt], 0, 0, 0);
      }

    // ---- tree max (max3-fusable, depth ~5) ----
    float mxa[4];
#pragma unroll
    for (int j = 0; j < 4; j++) {
      float a = fmaxf(fmaxf(sacc[0][j], sacc[0][j + 4]),
                      fmaxf(sacc[0][j + 8], sacc[0][j + 12]));
      float bb = fmaxf(fmaxf(sacc[1][j], sacc[1][j + 4]),
                       fmaxf(sacc[1][j + 8], sacc[1][j + 12]));
      mxa[j] = fmaxf(a, bb);
    }
    float mx = fmaxf(fmaxf(mxa[0], mxa[1]), fmaxf(mxa[2], mxa[3]));
    mx = fmaxf(mx, __shfl_xor(mx, 32, 64));

    // ---- defer-max: only rescale when the running max grew by > 8 ----
    if (!__all(mx <= m_run + 8.0f)) {
      float mnew = fmaxf(m_run, mx);
      float alpha = exp2_fast(m_run - mnew);
      m_run = mnew;
      l_run *= alpha;
#pragma unroll
      for (int r = 0; r < 16; r++) { o_acc[0][r] *= alpha; o_acc[1][r] *= alpha; }
    }

    // ---- P = exp2(S - m), 4-way split sum ----
    float ss0 = 0.0f, ss1 = 0.0f, ss2 = 0.0f, ss3 = 0.0f;
#pragma unroll
    for (int kvt = 0; kvt < 2; kvt++)
#pragma unroll
      for (int r = 0; r < 16; r += 4) {
        float p0 = exp2_fast(sacc[kvt][r + 0] - m_run);
        float p1 = exp2_fast(sacc[kvt][r + 1] - m_run);
        float p2 = exp2_fast(sacc[kvt][r + 2] - m_run);
        float p3 = exp2_fast(sacc[kvt][r + 3] - m_run);
        sacc[kvt][r + 0] = p0; sacc[kvt][r + 1] = p1;
        sacc[kvt][r + 2] = p2; sacc[kvt][r + 3] = p3;
        ss0 += p0; ss1 += p1; ss2 += p2; ss3 += p3;
      }
    float ssum = (ss0 + ss1) + (ss2 + ss3);
    ssum += __shfl_xor(ssum, 32, 64);
    l_run += ssum;

    // ---- P -> f16 B-fragments fully in-register (cvt_pkrtz + permlane32) ----
    f16x8 pf[4];
#pragma unroll
    for (int kvt = 0; kvt < 2; kvt++)
#pragma unroll
      for (int hf = 0; hf < 2; hf++) {
        const int h8 = hf * 8;
        int a0 = pk2(sacc[kvt][h8 + 0], sacc[kvt][h8 + 1]);
        int b0 = pk2(sacc[kvt][h8 + 4], sacc[kvt][h8 + 5]);
        int a1 = pk2(sacc[kvt][h8 + 2], sacc[kvt][h8 + 3]);
        int b1 = pk2(sacc[kvt][h8 + 6], sacc[kvt][h8 + 7]);
        permlane32_swap(a0, b0);   // a0 -> w0, b0 -> w2
        permlane32_swap(a1, b1);   // a1 -> w1, b1 -> w3
        union { int i[4]; f16x8 v; } u;
        u.i[0] = a0; u.i[1] = a1; u.i[2] = b0; u.i[3] = b1;
        pf[kvt * 2 + hf] = u.v;
      }

    // ---- O += V^T @ P ----
#pragma unroll
    for (int dt = 0; dt < 2; dt++) {
      const int d = dt * 32 + l31;
      const int dx = d >> 3;
#pragma unroll
      for (int ks = 0; ks < 4; ks++) {
        f16x8 va = *(const f16x8*)&Vt[d * 72 + (((ks * 2 + e) ^ dx) << 3)];
        o_acc[dt] = __builtin_amdgcn_mfma_f32_32x32x16_f16(va, pf[ks], o_acc[dt], 0, 0, 0);
      }
    }
    __syncthreads();
  }

  // ---- cross-half merge via LDS (one-time) ----
  // Om: [4 qw][32 q][68] f32 partial O of half 1; ML: [4 qw][m:32|l:32].
  float* Om = (float*)smem;
  float* ML = (float*)smem + 4 * 32 * 68;
  if (half == 1) {
#pragma unroll
    for (int dt = 0; dt < 2; dt++)
#pragma unroll
      for (int r2 = 0; r2 < 4; r2++) {
        f32x4 vv;
        vv[0] = o_acc[dt][r2 * 4 + 0];
        vv[1] = o_acc[dt][r2 * 4 + 1];
        vv[2] = o_acc[dt][r2 * 4 + 2];
        vv[3] = o_acc[dt][r2 * 4 + 3];
        *(f32x4*)&Om[(qw * 32 + l31) * 68 + dt * 32 + r2 * 8 + e * 4] = vv;
      }
    ML[qw * 64 + l31] = m_run;
    ML[qw * 64 + 32 + l31] = l_run;
  }
  __syncthreads();
  float linv = 0.0f;
  if (half == 0) {
    float m1 = ML[qw * 64 + l31], l1 = ML[qw * 64 + 32 + l31];
    float mm = fmaxf(m_run, m1);
    float a0 = exp2_fast(m_run - mm), a1 = exp2_fast(m1 - mm);
    linv = 1.0f / (l_run * a0 + l1 * a1);
#pragma unroll
    for (int dt = 0; dt < 2; dt++)
#pragma unroll
      for (int r2 = 0; r2 < 4; r2++) {
        f32x4 o1 = *(const f32x4*)&Om[(qw * 32 + l31) * 68 + dt * 32 + r2 * 8 + e * 4];
#pragma unroll
        for (int j = 0; j < 4; j++)
          o_acc[dt][r2 * 4 + j] = o_acc[dt][r2 * 4 + j] * a0 + o1[j] * a1;
      }
  }
  __syncthreads();

  // ---- epilogue (half 0 only): normalize, f16 reshuffle, coalesced write ----
  if (half == 0) {
    f16* Of = smem + qw * 32 * 72;  // [32 q][72] per-wave region
#pragma unroll
    for (int dt = 0; dt < 2; dt++)
#pragma unroll
      for (int r2 = 0; r2 < 4; r2++) {
        f16x2 h0 = pk2h(o_acc[dt][r2 * 4 + 0] * linv, o_acc[dt][r2 * 4 + 1] * linv);
        f16x2 h1 = pk2h(o_acc[dt][r2 * 4 + 2] * linv, o_acc[dt][r2 * 4 + 3] * linv);
        f16x4 hh; hh[0] = h0[0]; hh[1] = h0[1]; hh[2] = h1[0]; hh[3] = h1[1];
        *(f16x4*)&Of[l31 * 72 + dt * 32 + r2 * 8 + e * 4] = hh;
      }
    const int qq = lane >> 1, dh = (lane & 1) * 32;
#pragma unroll
    for (int j = 0; j < 4; j++) {
      f16x8 v = *(const f16x8*)&Of[qq * 72 + dh + j * 8];
      *(f16x8*)&Yh[(qrow0 + qw * 32 + qq) * 1024 + h * 64 + dh + j * 8] = v;
    }
  }
}

// ---------------------------------------------------------------------------
extern "C" void kernel_launch(void* const* d_in, const int* in_sizes, int n_in,
                              void* d_out, int out_size, void* d_ws, size_t ws_size,
                              hipStream_t stream) {
  const float* x_q  = (const float*)d_in[0];
  const float* x_kv = (const float*)d_in[1];
  const float* W_q  = (const float*)d_in[2];
  const float* W_kv = (const float*)d_in[3];
  const float* W_p  = (const float*)d_in[4];
  float* out = (float*)d_out;

  f16* Wq_t  = (f16*)d_ws;                       // [1024][1024]
  f16* Wkv_t = Wq_t  + (size_t)1024 * 1024;      // [2048][1024]
  f16* Wp_t  = Wkv_t + (size_t)2048 * 1024;      // [1024][1024]
  f16* Qh    = Wp_t  + (size_t)1024 * 1024;      // [4096][1024]
  f16* KVh   = Qh    + (size_t)4096 * 1024;      // [4096][2048]
  f16* Yh    = KVh   + (size_t)4096 * 2048;      // [4096][1024]
  f16* Xq_h  = Yh;                               // alias (dead after qkv_gemm)
  f16* Xkv_h = Yh    + (size_t)4096 * 1024;      // [4096][1024]

  prep<<<12288, 256, 0, stream>>>(x_q, x_kv, Xq_h, Xkv_h,
                                  W_q, W_kv, W_p, Wq_t, Wkv_t, Wp_t);

  const float SC = 11.5415603f;  // 8 * log2(e)
  qkv_gemm<<<768, 256, 0, stream>>>(Xq_h, Wq_t, Qh, Xkv_h, Wkv_t, KVh, SC);

  attn_kernel<<<512, 512, 0, stream>>>(Qh, KVh, Yh);

  gemm_lds<64, float><<<512, 256, 0, stream>>>(Yh, Wp_t, out, 4096, 1024, 1024, 1.0f);
}

// Round 4
// 203.512 us; speedup vs baseline: 1.0175x; 1.0017x over previous
//
#include <hip/hip_runtime.h>
#include <cstddef>

typedef _Float16 f16;
typedef _Float16 f16x8 __attribute__((ext_vector_type(8)));
typedef _Float16 f16x4 __attribute__((ext_vector_type(4)));
typedef _Float16 f16x2 __attribute__((ext_vector_type(2)));
typedef float f32x4 __attribute__((ext_vector_type(4)));
typedef float f32x16 __attribute__((ext_vector_type(16)));
typedef unsigned int u32;

__device__ inline float exp2_fast(float x) {
  float r;
  asm("v_exp_f32 %0, %1" : "=v"(r) : "v"(x));
  return r;
}

// pack two f32 -> f16x2 word (RTZ), as int for cross-lane ops
__device__ inline int pk2(float x, float y) {
  return __builtin_bit_cast(int, __builtin_amdgcn_cvt_pkrtz(x, y));
}

__device__ inline f16x2 pk2h(float x, float y) {
  return __builtin_bit_cast(f16x2, __builtin_amdgcn_cvt_pkrtz(x, y));
}

// v_permlane32_swap_b32: new_a[32:63] = old_b[0:31], new_b[0:31] = old_a[32:63]
__device__ inline void permlane32_swap(int& a, int& b) {
  asm volatile("v_permlane32_swap_b32 %0, %1" : "+v"(a), "+v"(b));
}

// global->LDS DMA, 16B per lane. LDS dest is wave-uniform base + lane*16;
// global src is per-lane.
__device__ __forceinline__ void gload16(const f16* g, f16* l) {
  __builtin_amdgcn_global_load_lds(
      (const __attribute__((address_space(1))) void*)g,
      (__attribute__((address_space(3))) void*)l, 16, 0, 0);
}

// ---------------------------------------------------------------------------
// Fused prep (unchanged): blocks [0,8192) stream-convert x_q/x_kv f32->f16;
// blocks [8192,12288) transpose+convert the three weight matrices.
// ---------------------------------------------------------------------------
__global__ __launch_bounds__(256) void prep(
    const float* __restrict__ xq, const float* __restrict__ xkv,
    f16* __restrict__ oq, f16* __restrict__ okv,
    const float* __restrict__ Wq, const float* __restrict__ Wkv,
    const float* __restrict__ Wp, f16* __restrict__ Wqt,
    f16* __restrict__ Wkvt, f16* __restrict__ Wpt) {
  __shared__ float t[32][33];
  int bid = blockIdx.x;
  if (bid < 8192) {
    const float* in = (bid < 4096) ? xq : xkv;
    f16* out = (bid < 4096) ? oq : okv;
    int i = ((bid & 4095) * 256 + threadIdx.x) * 4;
    float4 v = *(const float4*)&in[i];
    f16x4 h;
    h[0] = (f16)v.x; h[1] = (f16)v.y; h[2] = (f16)v.z; h[3] = (f16)v.w;
    *(f16x4*)&out[i] = h;
  } else {
    int zz = bid - 8192;
    int bx = zz & 31, by = (zz >> 5) & 31, z = zz >> 10;
    const float* in;
    f16* out;
    int N = 1024, extra = 0;
    if (z == 0) { in = Wq; out = Wqt; }
    else if (z == 3) { in = Wp; out = Wpt; }
    else { in = Wkv; out = Wkvt; N = 2048; extra = (z - 1) * 1024; }
    int tx = threadIdx.x % 32, ty = threadIdx.x / 32;
    int n0 = bx * 32 + extra, k0 = by * 32;
#pragma unroll
    for (int i = 0; i < 32; i += 8)
      t[ty + i][tx] = in[(size_t)(k0 + ty + i) * N + n0 + tx];
    __syncthreads();
#pragma unroll
    for (int i = 0; i < 32; i += 8)
      out[(size_t)(n0 + ty + i) * 1024 + k0 + tx] = (f16)t[tx][ty + i];
  }
}

// ---------------------------------------------------------------------------
// GEMM body, round 10: m97-pattern DMA staging.
// Round-9 post-mortem put both GEMMs at ~55-60us (~430/160 TF) -- reg-staged
// 2-phase is the documented ~600 TF structure; global_load_lds(16B) +
// LINEAR single-buffered LDS + 2 barriers/K-step measures 874-912 TF
// (m97/m151; XOR-swizzle is null at 2-phase, m228d/m230). Plus T1
// XCD-bijective tile swizzle so blocks sharing an A-panel land on the same
// XCD L2 (A was being re-fetched up to 8x).
// BM=128, BN templated, BK=64, 256 thr = 4 waves (2x2), 16x16x32 MFMA.
// ---------------------------------------------------------------------------
template <int BN, typename CT>
__device__ __forceinline__ void gemm_body(
    const f16* __restrict__ A, const f16* __restrict__ Bt, CT* __restrict__ C,
    int bid, int M, int N, int K, float scale, f16* As, f16* Bs) {
  constexpr int NT = BN / 32;
  const int nb = N / BN;
  // T1: bijective XCD swizzle (all grids here are multiples of 8)
  const int nwg = (M / 128) * nb;
  const int sbid = (bid & 7) * (nwg >> 3) + (bid >> 3);
  const int m0 = (sbid / nb) * 128;
  const int n0 = (sbid % nb) * BN;
  const int tid = threadIdx.x;
  const int w = tid >> 6, lane = tid & 63;
  const int l16 = lane & 15, quad = lane >> 4;
  const int wrow = (w >> 1) * 64, wcol = (w & 1) * (BN / 2);
  // DMA staging geometry: each wave-instr covers 8 rows x 64 cols (1 KB);
  // lane l -> row +l/8, col chunk (l%8)*8.
  const int lrow = lane >> 3, lcol = (lane & 7) * 8;

  f32x4 acc[4][NT] = {};

  for (int k0 = 0; k0 < K; k0 += 64) {
    // ---- stage tile k0 via global_load_lds (linear LDS) ----
#pragma unroll
    for (int i = 0; i < 4; i++) {
      const int r = w * 32 + i * 8;
      gload16(&A[(size_t)(m0 + r + lrow) * K + k0 + lcol], &As[r * 64]);
    }
#pragma unroll
    for (int i = 0; i < NT; i++) {
      const int r = w * (BN / 4) + i * 8;
      gload16(&Bt[(size_t)(n0 + r + lrow) * K + k0 + lcol], &Bs[r * 64]);
    }
    __syncthreads();  // drains vmcnt(0) -> tile resident

    // ---- fragments (linear reads) + MFMA ----
    f16x8 bf[NT][2];
#pragma unroll
    for (int nt = 0; nt < NT; nt++) {
      const int row = wcol + nt * 16 + l16;
#pragma unroll
      for (int s = 0; s < 2; s++)
        bf[nt][s] = *(const f16x8*)&Bs[row * 64 + s * 32 + quad * 8];
    }
#pragma unroll
    for (int mt = 0; mt < 4; mt++) {
      const int row = wrow + mt * 16 + l16;
      f16x8 af0 = *(const f16x8*)&As[row * 64 + quad * 8];
      f16x8 af1 = *(const f16x8*)&As[row * 64 + 32 + quad * 8];
#pragma unroll
      for (int nt = 0; nt < NT; nt++) {
        acc[mt][nt] = __builtin_amdgcn_mfma_f32_16x16x32_f16(af0, bf[nt][0], acc[mt][nt], 0, 0, 0);
        acc[mt][nt] = __builtin_amdgcn_mfma_f32_16x16x32_f16(af1, bf[nt][1], acc[mt][nt], 0, 0, 0);
      }
    }
    __syncthreads();  // compute done before next stage overwrites
  }

#pragma unroll
  for (int mt = 0; mt < 4; mt++)
#pragma unroll
    for (int nt = 0; nt < NT; nt++)
#pragma unroll
      for (int r = 0; r < 4; r++) {
        int row = m0 + wrow + mt * 16 + quad * 4 + r;
        int col = n0 + wcol + nt * 16 + l16;
        C[(size_t)row * N + col] = (CT)(acc[mt][nt][r] * scale);
      }
}

// Fused Q + KV projection GEMMs.
__global__ __launch_bounds__(256, 3) void qkv_gemm(
    const f16* __restrict__ Xq, const f16* __restrict__ Wqt, f16* __restrict__ Qh,
    const f16* __restrict__ Xkv, const f16* __restrict__ Wkvt, f16* __restrict__ KVh,
    float sc_q) {
  __shared__ f16 As[128 * 64];
  __shared__ f16 Bs[128 * 64];
  if (blockIdx.x < 256)
    gemm_body<128, f16>(Xq, Wqt, Qh, blockIdx.x, 4096, 1024, 1024, sc_q, As, Bs);
  else
    gemm_body<128, f16>(Xkv, Wkvt, KVh, blockIdx.x - 256, 4096, 2048, 1024, 1.0f, As, Bs);
}

template <int BN, typename CT>
__global__ __launch_bounds__(256, 2) void gemm_lds(
    const f16* __restrict__ A, const f16* __restrict__ Bt, CT* __restrict__ C,
    int M, int N, int K, float scale) {
  __shared__ f16 As[128 * 64];
  __shared__ f16 Bs[BN * 64];
  gemm_body<BN, CT>(A, Bt, C, blockIdx.x, M, N, K, scale, As, Bs);
}

// ---------------------------------------------------------------------------
// Flash attention (unchanged from round 9, control): KV-split, 8 waves,
// in-register P via cvt_pkrtz+permlane32_swap, defer-max, cross-half merge.
// ---------------------------------------------------------------------------
__global__ __launch_bounds__(512, 4) void attn_kernel(
    const f16* __restrict__ Qh, const f16* __restrict__ KVh, f16* __restrict__ Yh) {
  __shared__ f16 smem[18432];  // 36864 B

  const int bid = blockIdx.x;
  const int hb = bid & 31;
  const int qt = bid >> 5;
  const int h = hb >> 1, b = hb & 1;
  const int tid = threadIdx.x;
  const int w = tid >> 6, lane = tid & 63;
  const int l31 = lane & 31, e = lane >> 5;
  const int qw = w & 3, half = w >> 2;
  const int tl = tid & 255;  // staging index within the half

  f16* Ks = smem + half * (2 * 64 * 72);  // this half's K tile [64 kv][72]
  f16* Vt = Ks + 64 * 72;                 // this half's V^T tile [64 d][72]

  const size_t qrow0 = (size_t)b * 2048 + (size_t)qt * 128;
  const size_t kvrow0 = (size_t)b * 2048 + (size_t)half * 1024;

  f16x8 qf[4];
#pragma unroll
  for (int ks = 0; ks < 4; ks++)
    qf[ks] = *(const f16x8*)&Qh[(qrow0 + qw * 32 + l31) * 1024 + h * 64 + ks * 16 + e * 8];

  float m_run = -1e30f, l_run = 0.0f;
  f32x16 o_acc[2] = {};

  const int ksr = tl >> 2, ksc = (tl & 3) << 4;
  const int vkv0 = (tl >> 3) * 2;
  const int vd0 = (tl & 7) * 8;
  const int vcol = ((((vkv0 >> 3) ^ (tl & 7)) << 3) | (vkv0 & 7));

  f16x8 kr0, kr1, vr0, vr1;
  {
    const f16* kb = &KVh[(kvrow0 + ksr) * 2048 + h * 64 + ksc];
    kr0 = *(const f16x8*)kb;
    kr1 = *(const f16x8*)(kb + 8);
    const f16* vb = &KVh[(kvrow0 + vkv0) * 2048 + 1024 + h * 64 + vd0];
    vr0 = *(const f16x8*)vb;
    vr1 = *(const f16x8*)(vb + 2048);
  }

  for (int t = 0; t < 16; t++) {
    *(f16x8*)&Ks[ksr * 72 + ksc] = kr0;
    *(f16x8*)&Ks[ksr * 72 + ksc + 8] = kr1;
#pragma unroll
    for (int j = 0; j < 8; j++) {
      f16x2 p; p[0] = vr0[j]; p[1] = vr1[j];
      *(f16x2*)&Vt[(vd0 + j) * 72 + vcol] = p;
    }
    __syncthreads();

    if (t + 1 < 16) {
      const f16* kb = &KVh[(kvrow0 + (t + 1) * 64 + ksr) * 2048 + h * 64 + ksc];
      kr0 = *(const f16x8*)kb;
      kr1 = *(const f16x8*)(kb + 8);
      const f16* vb = &KVh[(kvrow0 + (t + 1) * 64 + vkv0) * 2048 + 1024 + h * 64 + vd0];
      vr0 = *(const f16x8*)vb;
      vr1 = *(const f16x8*)(vb + 2048);
    }

    // ---- S = K @ Q^T : lane(q=l31,e) reg r holds kv=(r&3)+8*(r>>2)+4e ----
    f32x16 sacc[2] = {};
#pragma unroll
    for (int kvt = 0; kvt < 2; kvt++)
#pragma unroll
      for (int ks = 0; ks < 4; ks++) {
        f16x8 a = *(const f16x8*)&Ks[(kvt * 32 + l31) * 72 + ks * 16 + e * 8];
        sacc[kvt] = __builtin_amdgcn_mfma_f32_32x32x16_f16(a, qf[ks], sacc[kvt], 0, 0, 0);
      }

    // ---- tree max (max3-fusable, depth ~5) ----
    float mxa[4];
#pragma unroll
    for (int j = 0; j < 4; j++) {
      float a = fmaxf(fmaxf(sacc[0][j], sacc[0][j + 4]),
                      fmaxf(sacc[0][j + 8], sacc[0][j + 12]));
      float bb = fmaxf(fmaxf(sacc[1][j], sacc[1][j + 4]),
                       fmaxf(sacc[1][j + 8], sacc[1][j + 12]));
      mxa[j] = fmaxf(a, bb);
    }
    float mx = fmaxf(fmaxf(mxa[0], mxa[1]), fmaxf(mxa[2], mxa[3]));
    mx = fmaxf(mx, __shfl_xor(mx, 32, 64));

    // ---- defer-max: only rescale when the running max grew by > 8 ----
    if (!__all(mx <= m_run + 8.0f)) {
      float mnew = fmaxf(m_run, mx);
      float alpha = exp2_fast(m_run - mnew);
      m_run = mnew;
      l_run *= alpha;
#pragma unroll
      for (int r = 0; r < 16; r++) { o_acc[0][r] *= alpha; o_acc[1][r] *= alpha; }
    }

    // ---- P = exp2(S - m), 4-way split sum ----
    float ss0 = 0.0f, ss1 = 0.0f, ss2 = 0.0f, ss3 = 0.0f;
#pragma unroll
    for (int kvt = 0; kvt < 2; kvt++)
#pragma unroll
      for (int r = 0; r < 16; r += 4) {
        float p0 = exp2_fast(sacc[kvt][r + 0] - m_run);
        float p1 = exp2_fast(sacc[kvt][r + 1] - m_run);
        float p2 = exp2_fast(sacc[kvt][r + 2] - m_run);
        float p3 = exp2_fast(sacc[kvt][r + 3] - m_run);
        sacc[kvt][r + 0] = p0; sacc[kvt][r + 1] = p1;
        sacc[kvt][r + 2] = p2; sacc[kvt][r + 3] = p3;
        ss0 += p0; ss1 += p1; ss2 += p2; ss3 += p3;
      }
    float ssum = (ss0 + ss1) + (ss2 + ss3);
    ssum += __shfl_xor(ssum, 32, 64);
    l_run += ssum;

    // ---- P -> f16 B-fragments fully in-register (cvt_pkrtz + permlane32) ----
    f16x8 pf[4];
#pragma unroll
    for (int kvt = 0; kvt < 2; kvt++)
#pragma unroll
      for (int hf = 0; hf < 2; hf++) {
        const int h8 = hf * 8;
        int a0 = pk2(sacc[kvt][h8 + 0], sacc[kvt][h8 + 1]);
        int b0 = pk2(sacc[kvt][h8 + 4], sacc[kvt][h8 + 5]);
        int a1 = pk2(sacc[kvt][h8 + 2], sacc[kvt][h8 + 3]);
        int b1 = pk2(sacc[kvt][h8 + 6], sacc[kvt][h8 + 7]);
        permlane32_swap(a0, b0);   // a0 -> w0, b0 -> w2
        permlane32_swap(a1, b1);   // a1 -> w1, b1 -> w3
        union { int i[4]; f16x8 v; } u;
        u.i[0] = a0; u.i[1] = a1; u.i[2] = b0; u.i[3] = b1;
        pf[kvt * 2 + hf] = u.v;
      }

    // ---- O += V^T @ P ----
#pragma unroll
    for (int dt = 0; dt < 2; dt++) {
      const int d = dt * 32 + l31;
      const int dx = d >> 3;
#pragma unroll
      for (int ks = 0; ks < 4; ks++) {
        f16x8 va = *(const f16x8*)&Vt[d * 72 + (((ks * 2 + e) ^ dx) << 3)];
        o_acc[dt] = __builtin_amdgcn_mfma_f32_32x32x16_f16(va, pf[ks], o_acc[dt], 0, 0, 0);
      }
    }
    __syncthreads();
  }

  // ---- cross-half merge via LDS (one-time) ----
  float* Om = (float*)smem;
  float* ML = (float*)smem + 4 * 32 * 68;
  if (half == 1) {
#pragma unroll
    for (int dt = 0; dt < 2; dt++)
#pragma unroll
      for (int r2 = 0; r2 < 4; r2++) {
        f32x4 vv;
        vv[0] = o_acc[dt][r2 * 4 + 0];
        vv[1] = o_acc[dt][r2 * 4 + 1];
        vv[2] = o_acc[dt][r2 * 4 + 2];
        vv[3] = o_acc[dt][r2 * 4 + 3];
        *(f32x4*)&Om[(qw * 32 + l31) * 68 + dt * 32 + r2 * 8 + e * 4] = vv;
      }
    ML[qw * 64 + l31] = m_run;
    ML[qw * 64 + 32 + l31] = l_run;
  }
  __syncthreads();
  float linv = 0.0f;
  if (half == 0) {
    float m1 = ML[qw * 64 + l31], l1 = ML[qw * 64 + 32 + l31];
    float mm = fmaxf(m_run, m1);
    float a0 = exp2_fast(m_run - mm), a1 = exp2_fast(m1 - mm);
    linv = 1.0f / (l_run * a0 + l1 * a1);
#pragma unroll
    for (int dt = 0; dt < 2; dt++)
#pragma unroll
      for (int r2 = 0; r2 < 4; r2++) {
        f32x4 o1 = *(const f32x4*)&Om[(qw * 32 + l31) * 68 + dt * 32 + r2 * 8 + e * 4];
#pragma unroll
        for (int j = 0; j < 4; j++)
          o_acc[dt][r2 * 4 + j] = o_acc[dt][r2 * 4 + j] * a0 + o1[j] * a1;
      }
  }
  __syncthreads();

  // ---- epilogue (half 0 only): normalize, f16 reshuffle, coalesced write ----
  if (half == 0) {
    f16* Of = smem + qw * 32 * 72;  // [32 q][72] per-wave region
#pragma unroll
    for (int dt = 0; dt < 2; dt++)
#pragma unroll
      for (int r2 = 0; r2 < 4; r2++) {
        f16x2 h0 = pk2h(o_acc[dt][r2 * 4 + 0] * linv, o_acc[dt][r2 * 4 + 1] * linv);
        f16x2 h1 = pk2h(o_acc[dt][r2 * 4 + 2] * linv, o_acc[dt][r2 * 4 + 3] * linv);
        f16x4 hh; hh[0] = h0[0]; hh[1] = h0[1]; hh[2] = h1[0]; hh[3] = h1[1];
        *(f16x4*)&Of[l31 * 72 + dt * 32 + r2 * 8 + e * 4] = hh;
      }
    const int qq = lane >> 1, dh = (lane & 1) * 32;
#pragma unroll
    for (int j = 0; j < 4; j++) {
      f16x8 v = *(const f16x8*)&Of[qq * 72 + dh + j * 8];
      *(f16x8*)&Yh[(qrow0 + qw * 32 + qq) * 1024 + h * 64 + dh + j * 8] = v;
    }
  }
}

// ---------------------------------------------------------------------------
extern "C" void kernel_launch(void* const* d_in, const int* in_sizes, int n_in,
                              void* d_out, int out_size, void* d_ws, size_t ws_size,
                              hipStream_t stream) {
  const float* x_q  = (const float*)d_in[0];
  const float* x_kv = (const float*)d_in[1];
  const float* W_q  = (const float*)d_in[2];
  const float* W_kv = (const float*)d_in[3];
  const float* W_p  = (const float*)d_in[4];
  float* out = (float*)d_out;

  f16* Wq_t  = (f16*)d_ws;                       // [1024][1024]
  f16* Wkv_t = Wq_t  + (size_t)1024 * 1024;      // [2048][1024]
  f16* Wp_t  = Wkv_t + (size_t)2048 * 1024;      // [1024][1024]
  f16* Qh    = Wp_t  + (size_t)1024 * 1024;      // [4096][1024]
  f16* KVh   = Qh    + (size_t)4096 * 1024;      // [4096][2048]
  f16* Yh    = KVh   + (size_t)4096 * 2048;      // [4096][1024]
  f16* Xq_h  = Yh;                               // alias (dead after qkv_gemm)
  f16* Xkv_h = Yh    + (size_t)4096 * 1024;      // [4096][1024]

  prep<<<12288, 256, 0, stream>>>(x_q, x_kv, Xq_h, Xkv_h,
                                  W_q, W_kv, W_p, Wq_t, Wkv_t, Wp_t);

  const float SC = 11.5415603f;  // 8 * log2(e)
  qkv_gemm<<<768, 256, 0, stream>>>(Xq_h, Wq_t, Qh, Xkv_h, Wkv_t, KVh, SC);

  attn_kernel<<<512, 512, 0, stream>>>(Qh, KVh, Yh);

  gemm_lds<64, float><<<512, 256, 0, stream>>>(Yh, Wp_t, out, 4096, 1024, 1024, 1.0f);
}

// Round 5
// 203.102 us; speedup vs baseline: 1.0195x; 1.0020x over previous
//
#include <hip/hip_runtime.h>
#include <cstddef>

typedef _Float16 f16;
typedef _Float16 f16x8 __attribute__((ext_vector_type(8)));
typedef _Float16 f16x4 __attribute__((ext_vector_type(4)));
typedef _Float16 f16x2 __attribute__((ext_vector_type(2)));
typedef float f32x4 __attribute__((ext_vector_type(4)));
typedef float f32x16 __attribute__((ext_vector_type(16)));
typedef unsigned int u32;

__device__ inline float exp2_fast(float x) {
  float r;
  asm("v_exp_f32 %0, %1" : "=v"(r) : "v"(x));
  return r;
}

// pack two f32 -> f16x2 word (RTZ), as int for cross-lane ops
__device__ inline int pk2(float x, float y) {
  return __builtin_bit_cast(int, __builtin_amdgcn_cvt_pkrtz(x, y));
}

__device__ inline f16x2 pk2h(float x, float y) {
  return __builtin_bit_cast(f16x2, __builtin_amdgcn_cvt_pkrtz(x, y));
}

// v_permlane32_swap_b32: new_a[32:63] = old_b[0:31], new_b[0:31] = old_a[32:63]
__device__ inline void permlane32_swap(int& a, int& b) {
  asm volatile("v_permlane32_swap_b32 %0, %1" : "+v"(a), "+v"(b));
}

// global->LDS DMA, 16B per lane. LDS dest is wave-uniform base + lane*16;
// global src is per-lane (so swizzles are applied by permuting the SOURCE).
__device__ __forceinline__ void gload16(const f16* g, f16* l) {
  __builtin_amdgcn_global_load_lds(
      (const __attribute__((address_space(1))) void*)g,
      (__attribute__((address_space(3))) void*)l, 16, 0, 0);
}

// ---------------------------------------------------------------------------
// Fused prep (unchanged, control): blocks [0,8192) stream-convert x f32->f16;
// blocks [8192,12288) transpose+convert the three weight matrices.
// ---------------------------------------------------------------------------
__global__ __launch_bounds__(256) void prep(
    const float* __restrict__ xq, const float* __restrict__ xkv,
    f16* __restrict__ oq, f16* __restrict__ okv,
    const float* __restrict__ Wq, const float* __restrict__ Wkv,
    const float* __restrict__ Wp, f16* __restrict__ Wqt,
    f16* __restrict__ Wkvt, f16* __restrict__ Wpt) {
  __shared__ float t[32][33];
  int bid = blockIdx.x;
  if (bid < 8192) {
    const float* in = (bid < 4096) ? xq : xkv;
    f16* out = (bid < 4096) ? oq : okv;
    int i = ((bid & 4095) * 256 + threadIdx.x) * 4;
    float4 v = *(const float4*)&in[i];
    f16x4 h;
    h[0] = (f16)v.x; h[1] = (f16)v.y; h[2] = (f16)v.z; h[3] = (f16)v.w;
    *(f16x4*)&out[i] = h;
  } else {
    int zz = bid - 8192;
    int bx = zz & 31, by = (zz >> 5) & 31, z = zz >> 10;
    const float* in;
    f16* out;
    int N = 1024, extra = 0;
    if (z == 0) { in = Wq; out = Wqt; }
    else if (z == 3) { in = Wp; out = Wpt; }
    else { in = Wkv; out = Wkvt; N = 2048; extra = (z - 1) * 1024; }
    int tx = threadIdx.x % 32, ty = threadIdx.x / 32;
    int n0 = bx * 32 + extra, k0 = by * 32;
#pragma unroll
    for (int i = 0; i < 32; i += 8)
      t[ty + i][tx] = in[(size_t)(k0 + ty + i) * N + n0 + tx];
    __syncthreads();
#pragma unroll
    for (int i = 0; i < 32; i += 8)
      out[(size_t)(n0 + ty + i) * 1024 + k0 + tx] = (f16)t[tx][ty + i];
  }
}

// ---------------------------------------------------------------------------
// GEMM body, round 11: double-buffered 2-phase DMA pipeline (T3 minimum).
// Round-10 post-mortem: m97-style stage->drain->compute was NEUTRAL vs
// reg-staging -- at K=1024 the per-K-step full vmcnt drain before compute
// exposes the whole HBM latency (m233: stage+vmcnt+barrier = 72% of 2ph).
// New schedule per K-step: STAGE(buf^1, t+1) issued FIRST, compute(buf),
// then ONE __syncthreads() (its vmcnt(0) lands after compute has covered
// the load latency), swap. Barriers 2->1, latency overlapped in-wave.
// LDS-read conflicts now matter (critical path moves off staging), so
// rule-21 both-sides swizzle: pre-swizzled GLOBAL source (gload LDS dest
// must stay linear) + XOR-swizzled fragment reads.
// BM=128, BN templated, BK=64, 256 thr = 4 waves (2x2), 16x16x32 MFMA.
// ---------------------------------------------------------------------------
template <int BN, typename CT>
__device__ __forceinline__ void gemm_body(
    const f16* __restrict__ A, const f16* __restrict__ Bt, CT* __restrict__ C,
    int bid, int M, int N, int K, float scale, f16* As, f16* Bs) {
  constexpr int NT = BN / 32;
  constexpr int ASZ = 128 * 64;   // halfs per A buffer
  constexpr int BSZ = BN * 64;    // halfs per B buffer
  const int nb = N / BN;
  // T1: bijective XCD swizzle (all grids here are multiples of 8)
  const int nwg = (M / 128) * nb;
  const int sbid = (bid & 7) * (nwg >> 3) + (bid >> 3);
  const int m0 = (sbid / nb) * 128;
  const int n0 = (sbid % nb) * BN;
  const int tid = threadIdx.x;
  const int w = tid >> 6, lane = tid & 63;
  const int l16 = lane & 15, quad = lane >> 4;
  const int wrow = (w >> 1) * 64, wcol = (w & 1) * (BN / 2);
  // DMA staging geometry: one wave-instr covers 8 rows x 64 cols (1 KB).
  // Source col-chunk is pre-swizzled so LDS slot (row, c) holds data chunk
  // c ^ (row&7)  (row0 of each gload is 8-aligned -> (row&7) == lane>>3).
  const int lrow = lane >> 3;
  const int lcs = (((lane & 7) ^ (lane >> 3)) & 7) * 8;

  f32x4 acc[4][NT] = {};

#define STAGE_TILE(bp, kk)                                                   \
  {                                                                          \
    _Pragma("unroll") for (int i = 0; i < 4; i++) {                          \
      const int r = w * 32 + i * 8;                                          \
      gload16(&A[(size_t)(m0 + r + lrow) * K + (kk) + lcs],                  \
              &As[(bp) * ASZ + r * 64]);                                     \
    }                                                                        \
    _Pragma("unroll") for (int i = 0; i < NT; i++) {                         \
      const int r = w * (BN / 4) + i * 8;                                    \
      gload16(&Bt[(size_t)(n0 + r + lrow) * K + (kk) + lcs],                 \
              &Bs[(bp) * BSZ + r * 64]);                                     \
    }                                                                        \
  }

  STAGE_TILE(0, 0);
  __syncthreads();  // tile 0 resident

  int buf = 0;
  for (int k0 = 0; k0 < K; k0 += 64) {
    // ---- issue next tile's DMA first (latency hides under compute) ----
    if (k0 + 64 < K) STAGE_TILE(buf ^ 1, k0 + 64);

    const f16* Asb = &As[buf * ASZ];
    const f16* Bsb = &Bs[buf * BSZ];

    // ---- fragments (swizzled reads, 8-phase bank floor) + MFMA ----
    f16x8 bf[NT][2];
#pragma unroll
    for (int nt = 0; nt < NT; nt++) {
      const int row = wcol + nt * 16 + l16;
#pragma unroll
      for (int s = 0; s < 2; s++)
        bf[nt][s] = *(const f16x8*)&Bsb[row * 64 + (((s * 4 + quad) ^ (row & 7)) << 3)];
    }
#pragma unroll
    for (int mt = 0; mt < 4; mt++) {
      const int row = wrow + mt * 16 + l16;
      f16x8 af0 = *(const f16x8*)&Asb[row * 64 + ((quad ^ (row & 7)) << 3)];
      f16x8 af1 = *(const f16x8*)&Asb[row * 64 + (((4 + quad) ^ (row & 7)) << 3)];
#pragma unroll
      for (int nt = 0; nt < NT; nt++) {
        acc[mt][nt] = __builtin_amdgcn_mfma_f32_16x16x32_f16(af0, bf[nt][0], acc[mt][nt], 0, 0, 0);
        acc[mt][nt] = __builtin_amdgcn_mfma_f32_16x16x32_f16(af1, bf[nt][1], acc[mt][nt], 0, 0, 0);
      }
    }
    __syncthreads();  // drains vmcnt(0): next tile resident; buf reuse safe
    buf ^= 1;
  }
#undef STAGE_TILE

#pragma unroll
  for (int mt = 0; mt < 4; mt++)
#pragma unroll
    for (int nt = 0; nt < NT; nt++)
#pragma unroll
      for (int r = 0; r < 4; r++) {
        int row = m0 + wrow + mt * 16 + quad * 4 + r;
        int col = n0 + wcol + nt * 16 + l16;
        C[(size_t)row * N + col] = (CT)(acc[mt][nt][r] * scale);
      }
}

// Fused Q + KV projection GEMMs. dbuf LDS = 64 KB -> 2 blocks/CU.
__global__ __launch_bounds__(256, 2) void qkv_gemm(
    const f16* __restrict__ Xq, const f16* __restrict__ Wqt, f16* __restrict__ Qh,
    const f16* __restrict__ Xkv, const f16* __restrict__ Wkvt, f16* __restrict__ KVh,
    float sc_q) {
  __shared__ f16 As[2 * 128 * 64];
  __shared__ f16 Bs[2 * 128 * 64];
  if (blockIdx.x < 256)
    gemm_body<128, f16>(Xq, Wqt, Qh, blockIdx.x, 4096, 1024, 1024, sc_q, As, Bs);
  else
    gemm_body<128, f16>(Xkv, Wkvt, KVh, blockIdx.x - 256, 4096, 2048, 1024, 1.0f, As, Bs);
}

// proj: BN=64, dbuf LDS = 48 KB -> 3 blocks/CU.
template <int BN, typename CT>
__global__ __launch_bounds__(256, 3) void gemm_lds(
    const f16* __restrict__ A, const f16* __restrict__ Bt, CT* __restrict__ C,
    int M, int N, int K, float scale) {
  __shared__ f16 As[2 * 128 * 64];
  __shared__ f16 Bs[2 * BN * 64];
  gemm_body<BN, CT>(A, Bt, C, blockIdx.x, M, N, K, scale, As, Bs);
}

// ---------------------------------------------------------------------------
// Flash attention (unchanged from round 9, control): KV-split, 8 waves,
// in-register P via cvt_pkrtz+permlane32_swap, defer-max, cross-half merge.
// ---------------------------------------------------------------------------
__global__ __launch_bounds__(512, 4) void attn_kernel(
    const f16* __restrict__ Qh, const f16* __restrict__ KVh, f16* __restrict__ Yh) {
  __shared__ f16 smem[18432];  // 36864 B

  const int bid = blockIdx.x;
  const int hb = bid & 31;
  const int qt = bid >> 5;
  const int h = hb >> 1, b = hb & 1;
  const int tid = threadIdx.x;
  const int w = tid >> 6, lane = tid & 63;
  const int l31 = lane & 31, e = lane >> 5;
  const int qw = w & 3, half = w >> 2;
  const int tl = tid & 255;  // staging index within the half

  f16* Ks = smem + half * (2 * 64 * 72);  // this half's K tile [64 kv][72]
  f16* Vt = Ks + 64 * 72;                 // this half's V^T tile [64 d][72]

  const size_t qrow0 = (size_t)b * 2048 + (size_t)qt * 128;
  const size_t kvrow0 = (size_t)b * 2048 + (size_t)half * 1024;

  f16x8 qf[4];
#pragma unroll
  for (int ks = 0; ks < 4; ks++)
    qf[ks] = *(const f16x8*)&Qh[(qrow0 + qw * 32 + l31) * 1024 + h * 64 + ks * 16 + e * 8];

  float m_run = -1e30f, l_run = 0.0f;
  f32x16 o_acc[2] = {};

  const int ksr = tl >> 2, ksc = (tl & 3) << 4;
  const int vkv0 = (tl >> 3) * 2;
  const int vd0 = (tl & 7) * 8;
  const int vcol = ((((vkv0 >> 3) ^ (tl & 7)) << 3) | (vkv0 & 7));

  f16x8 kr0, kr1, vr0, vr1;
  {
    const f16* kb = &KVh[(kvrow0 + ksr) * 2048 + h * 64 + ksc];
    kr0 = *(const f16x8*)kb;
    kr1 = *(const f16x8*)(kb + 8);
    const f16* vb = &KVh[(kvrow0 + vkv0) * 2048 + 1024 + h * 64 + vd0];
    vr0 = *(const f16x8*)vb;
    vr1 = *(const f16x8*)(vb + 2048);
  }

  for (int t = 0; t < 16; t++) {
    *(f16x8*)&Ks[ksr * 72 + ksc] = kr0;
    *(f16x8*)&Ks[ksr * 72 + ksc + 8] = kr1;
#pragma unroll
    for (int j = 0; j < 8; j++) {
      f16x2 p; p[0] = vr0[j]; p[1] = vr1[j];
      *(f16x2*)&Vt[(vd0 + j) * 72 + vcol] = p;
    }
    __syncthreads();

    if (t + 1 < 16) {
      const f16* kb = &KVh[(kvrow0 + (t + 1) * 64 + ksr) * 2048 + h * 64 + ksc];
      kr0 = *(const f16x8*)kb;
      kr1 = *(const f16x8*)(kb + 8);
      const f16* vb = &KVh[(kvrow0 + (t + 1) * 64 + vkv0) * 2048 + 1024 + h * 64 + vd0];
      vr0 = *(const f16x8*)vb;
      vr1 = *(const f16x8*)(vb + 2048);
    }

    // ---- S = K @ Q^T : lane(q=l31,e) reg r holds kv=(r&3)+8*(r>>2)+4e ----
    f32x16 sacc[2] = {};
#pragma unroll
    for (int kvt = 0; kvt < 2; kvt++)
#pragma unroll
      for (int ks = 0; ks < 4; ks++) {
        f16x8 a = *(const f16x8*)&Ks[(kvt * 32 + l31) * 72 + ks * 16 + e * 8];
        sacc[kvt] = __builtin_amdgcn_mfma_f32_32x32x16_f16(a, qf[ks], sacc[kvt], 0, 0, 0);
      }

    // ---- tree max (max3-fusable, depth ~5) ----
    float mxa[4];
#pragma unroll
    for (int j = 0; j < 4; j++) {
      float a = fmaxf(fmaxf(sacc[0][j], sacc[0][j + 4]),
                      fmaxf(sacc[0][j + 8], sacc[0][j + 12]));
      float bb = fmaxf(fmaxf(sacc[1][j], sacc[1][j + 4]),
                       fmaxf(sacc[1][j + 8], sacc[1][j + 12]));
      mxa[j] = fmaxf(a, bb);
    }
    float mx = fmaxf(fmaxf(mxa[0], mxa[1]), fmaxf(mxa[2], mxa[3]));
    mx = fmaxf(mx, __shfl_xor(mx, 32, 64));

    // ---- defer-max: only rescale when the running max grew by > 8 ----
    if (!__all(mx <= m_run + 8.0f)) {
      float mnew = fmaxf(m_run, mx);
      float alpha = exp2_fast(m_run - mnew);
      m_run = mnew;
      l_run *= alpha;
#pragma unroll
      for (int r = 0; r < 16; r++) { o_acc[0][r] *= alpha; o_acc[1][r] *= alpha; }
    }

    // ---- P = exp2(S - m), 4-way split sum ----
    float ss0 = 0.0f, ss1 = 0.0f, ss2 = 0.0f, ss3 = 0.0f;
#pragma unroll
    for (int kvt = 0; kvt < 2; kvt++)
#pragma unroll
      for (int r = 0; r < 16; r += 4) {
        float p0 = exp2_fast(sacc[kvt][r + 0] - m_run);
        float p1 = exp2_fast(sacc[kvt][r + 1] - m_run);
        float p2 = exp2_fast(sacc[kvt][r + 2] - m_run);
        float p3 = exp2_fast(sacc[kvt][r + 3] - m_run);
        sacc[kvt][r + 0] = p0; sacc[kvt][r + 1] = p1;
        sacc[kvt][r + 2] = p2; sacc[kvt][r + 3] = p3;
        ss0 += p0; ss1 += p1; ss2 += p2; ss3 += p3;
      }
    float ssum = (ss0 + ss1) + (ss2 + ss3);
    ssum += __shfl_xor(ssum, 32, 64);
    l_run += ssum;

    // ---- P -> f16 B-fragments fully in-register (cvt_pkrtz + permlane32) ----
    f16x8 pf[4];
#pragma unroll
    for (int kvt = 0; kvt < 2; kvt++)
#pragma unroll
      for (int hf = 0; hf < 2; hf++) {
        const int h8 = hf * 8;
        int a0 = pk2(sacc[kvt][h8 + 0], sacc[kvt][h8 + 1]);
        int b0 = pk2(sacc[kvt][h8 + 4], sacc[kvt][h8 + 5]);
        int a1 = pk2(sacc[kvt][h8 + 2], sacc[kvt][h8 + 3]);
        int b1 = pk2(sacc[kvt][h8 + 6], sacc[kvt][h8 + 7]);
        permlane32_swap(a0, b0);   // a0 -> w0, b0 -> w2
        permlane32_swap(a1, b1);   // a1 -> w1, b1 -> w3
        union { int i[4]; f16x8 v; } u;
        u.i[0] = a0; u.i[1] = a1; u.i[2] = b0; u.i[3] = b1;
        pf[kvt * 2 + hf] = u.v;
      }

    // ---- O += V^T @ P ----
#pragma unroll
    for (int dt = 0; dt < 2; dt++) {
      const int d = dt * 32 + l31;
      const int dx = d >> 3;
#pragma unroll
      for (int ks = 0; ks < 4; ks++) {
        f16x8 va = *(const f16x8*)&Vt[d * 72 + (((ks * 2 + e) ^ dx) << 3)];
        o_acc[dt] = __builtin_amdgcn_mfma_f32_32x32x16_f16(va, pf[ks], o_acc[dt], 0, 0, 0);
      }
    }
    __syncthreads();
  }

  // ---- cross-half merge via LDS (one-time) ----
  float* Om = (float*)smem;
  float* ML = (float*)smem + 4 * 32 * 68;
  if (half == 1) {
#pragma unroll
    for (int dt = 0; dt < 2; dt++)
#pragma unroll
      for (int r2 = 0; r2 < 4; r2++) {
        f32x4 vv;
        vv[0] = o_acc[dt][r2 * 4 + 0];
        vv[1] = o_acc[dt][r2 * 4 + 1];
        vv[2] = o_acc[dt][r2 * 4 + 2];
        vv[3] = o_acc[dt][r2 * 4 + 3];
        *(f32x4*)&Om[(qw * 32 + l31) * 68 + dt * 32 + r2 * 8 + e * 4] = vv;
      }
    ML[qw * 64 + l31] = m_run;
    ML[qw * 64 + 32 + l31] = l_run;
  }
  __syncthreads();
  float linv = 0.0f;
  if (half == 0) {
    float m1 = ML[qw * 64 + l31], l1 = ML[qw * 64 + 32 + l31];
    float mm = fmaxf(m_run, m1);
    float a0 = exp2_fast(m_run - mm), a1 = exp2_fast(m1 - mm);
    linv = 1.0f / (l_run * a0 + l1 * a1);
#pragma unroll
    for (int dt = 0; dt < 2; dt++)
#pragma unroll
      for (int r2 = 0; r2 < 4; r2++) {
        f32x4 o1 = *(const f32x4*)&Om[(qw * 32 + l31) * 68 + dt * 32 + r2 * 8 + e * 4];
#pragma unroll
        for (int j = 0; j < 4; j++)
          o_acc[dt][r2 * 4 + j] = o_acc[dt][r2 * 4 + j] * a0 + o1[j] * a1;
      }
  }
  __syncthreads();

  // ---- epilogue (half 0 only): normalize, f16 reshuffle, coalesced write ----
  if (half == 0) {
    f16* Of = smem + qw * 32 * 72;  // [32 q][72] per-wave region
#pragma unroll
    for (int dt = 0; dt < 2; dt++)
#pragma unroll
      for (int r2 = 0; r2 < 4; r2++) {
        f16x2 h0 = pk2h(o_acc[dt][r2 * 4 + 0] * linv, o_acc[dt][r2 * 4 + 1] * linv);
        f16x2 h1 = pk2h(o_acc[dt][r2 * 4 + 2] * linv, o_acc[dt][r2 * 4 + 3] * linv);
        f16x4 hh; hh[0] = h0[0]; hh[1] = h0[1]; hh[2] = h1[0]; hh[3] = h1[1];
        *(f16x4*)&Of[l31 * 72 + dt * 32 + r2 * 8 + e * 4] = hh;
      }
    const int qq = lane >> 1, dh = (lane & 1) * 32;
#pragma unroll
    for (int j = 0; j < 4; j++) {
      f16x8 v = *(const f16x8*)&Of[qq * 72 + dh + j * 8];
      *(f16x8*)&Yh[(qrow0 + qw * 32 + qq) * 1024 + h * 64 + dh + j * 8] = v;
    }
  }
}

// ---------------------------------------------------------------------------
extern "C" void kernel_launch(void* const* d_in, const int* in_sizes, int n_in,
                              void* d_out, int out_size, void* d_ws, size_t ws_size,
                              hipStream_t stream) {
  const float* x_q  = (const float*)d_in[0];
  const float* x_kv = (const float*)d_in[1];
  const float* W_q  = (const float*)d_in[2];
  const float* W_kv = (const float*)d_in[3];
  const float* W_p  = (const float*)d_in[4];
  float* out = (float*)d_out;

  f16* Wq_t  = (f16*)d_ws;                       // [1024][1024]
  f16* Wkv_t = Wq_t  + (size_t)1024 * 1024;      // [2048][1024]
  f16* Wp_t  = Wkv_t + (size_t)2048 * 1024;      // [1024][1024]
  f16* Qh    = Wp_t  + (size_t)1024 * 1024;      // [4096][1024]
  f16* KVh   = Qh    + (size_t)4096 * 1024;      // [4096][2048]
  f16* Yh    = KVh   + (size_t)4096 * 2048;      // [4096][1024]
  f16* Xq_h  = Yh;                               // alias (dead after qkv_gemm)
  f16* Xkv_h = Yh    + (size_t)4096 * 1024;      // [4096][1024]

  prep<<<12288, 256, 0, stream>>>(x_q, x_kv, Xq_h, Xkv_h,
                                  W_q, W_kv, W_p, Wq_t, Wkv_t, Wp_t);

  const float SC = 11.5415603f;  // 8 * log2(e)
  qkv_gemm<<<768, 256, 0, stream>>>(Xq_h, Wq_t, Qh, Xkv_h, Wkv_t, KVh, SC);

  attn_kernel<<<512, 512, 0, stream>>>(Qh, KVh, Yh);

  gemm_lds<64, float><<<512, 256, 0, stream>>>(Yh, Wp_t, out, 4096, 1024, 1024, 1.0f);
}